// Round 15
// baseline (32.332 us; speedup 1.0000x reference)
//
#include <hip/hip_runtime.h>
#include <stdint.h>

#define BATCH 16
#define NPIX 200704      // 448*448
#define EPS 1e-6f
#define FW 128           // fine grid; i+j <= 127 structurally (chroma simplex)
#define NCHUNK 16        // pixel chunks per batch in K1
#define CHPX (NPIX / NCHUNK)     // 12544 pixels (u16-safe: < 65536)
#define CHF4 (CHPX / 4)          // 3136 float4 per plane
#define NTILE 3          // nonzero 64x64 tiles: it+jq <= 1
#define SLAB4 (NTILE * 512)      // uint4 per (b,chunk) slab

// tile list
__constant__ int c_itA[NTILE] = {0, 0, 1};
__constant__ int c_jqA[NTILE] = {0, 1, 0};

// K(c,g) = 1 / (1 + ((cc - b_g)/sigma)^2), cc=(c+0.5)/FW, b_g=g/63, 1/sigma=50
__device__ __forceinline__ float kval(int c, int g) {
  float d = (((float)c + 0.5f) * (1.0f / (float)FW) - (float)g * (1.0f / 63.0f)) * 50.0f;
  return 1.0f / (1.0f + d * d);
}

// ---------------- K1: full-grid u16 histogram per (batch, pixel-chunk) — R13 verbatim ----------------
__global__ __launch_bounds__(1024) void hist_full(const float* __restrict__ x,
                                                  unsigned int* __restrict__ Hq) {
  __shared__ unsigned int sh[8192];         // 16384 u16 bins (128x128), packed
  const int bid = blockIdx.x;
  const int tid = threadIdx.x;
  const int xcd = bid & 7;                  // batch pinned to XCD b%8
  const int t0 = bid >> 3;                  // 0..31
  const int chunk = t0 & (NCHUNK - 1);
  const int b = xcd + 8 * (t0 >> 4);

  {
    uint4* s4 = (uint4*)sh;
    uint4 z = make_uint4(0u, 0u, 0u, 0u);
    for (int t = tid; t < 2048; t += 1024) s4[t] = z;
  }
  __syncthreads();

  const float* xb = x + (size_t)b * 3 * NPIX;
  const float4* R  = (const float4*)xb + (size_t)chunk * CHF4;
  const float4* G  = (const float4*)(xb + NPIX) + (size_t)chunk * CHF4;
  const float4* Bl = (const float4*)(xb + 2 * NPIX) + (size_t)chunk * CHF4;

  for (int t = tid; t < CHF4; t += 1024) {
    float4 rv = R[t], gv = G[t], bv = Bl[t];
    float rr[4] = {rv.x, rv.y, rv.z, rv.w};
    float gg[4] = {gv.x, gv.y, gv.z, gv.w};
    float bb[4] = {bv.x, bv.y, bv.z, bv.w};
#pragma unroll
    for (int c = 0; c < 4; c++) {
      float r  = fminf(fmaxf(rr[c], 0.0f), 1.0f);
      float g  = fminf(fmaxf(gg[c], 0.0f), 1.0f);
      float bl = fminf(fmaxf(bb[c], 0.0f), 1.0f);
      float inv = 1.0f / (r + g + bl + EPS);
      int i = min((int)(r * inv * (float)FW), FW - 1);
      int j = min((int)(g * inv * (float)FW), FW - 1);
      unsigned int id = (unsigned int)((i << 7) | j);
      atomicAdd(&sh[id >> 1], 1u << ((id & 1u) << 4));   // packed u16; <=12544 adds
    }
  }
  __syncthreads();

  // flush the 3 nonzero 64x64 tiles
  const uint4* sh4 = (const uint4*)sh;
  uint4* dst = (uint4*)Hq + (size_t)(b * NCHUNK + chunk) * SLAB4;
  for (int t = tid; t < SLAB4; t += 1024) {
    int tno = t >> 9;
    int rem = t & 511;
    int row = rem >> 3, c4 = rem & 7;
    int it = c_itA[tno], jq = c_jqA[tno];
    dst[t] = sh4[(it * 64 + row) * 16 + jq * 8 + c4];
  }
}

// ---------------- K2: stage Hsum -> M-strip GEMM -> K^T epilogue -> self-normalize -> out ----------------
// block (b, strip of 8 g-cols). T computed in-block from staged Hsum (exact; identical
// across blocks: same data, same fixed order). 85.6 KB dynamic LDS.
__global__ __launch_bounds__(256) void bc_final(const unsigned int* __restrict__ Hq,
                                                float* __restrict__ out) {
  extern __shared__ char smem[];
  float (*sHf)[132] = (float (*)[132])smem;                 // 128x132 Hsum (f32)
  float (*sKC)[68]  = (float (*)[68])smem;                  // alias: K_C after M-phase
  float (*sKgT)[132] = (float (*)[132])(smem + 67584);      // 8x132: K(j,strip) transposed
  float* sS   = (float*)(smem + 71808);                     // 128: S(c)=sum_g K(c,g)
  float (*sM)[8] = (float (*)[8])(smem + 72320);            // 128x8 M strip
  float* sMp  = (float*)(smem + 76416);                     // 2x128x8 partials (alias sOp 4x64x8)
  float* sred = (float*)(smem + 84608);                     // 256

  const int bid = blockIdx.x;     // 128 = xcd(8) x strip(8) x bh(2)
  const int tid = threadIdx.x;
  const int xcd = bid & 7;
  const int t0 = bid >> 3;        // 0..15
  const int strip = t0 & 7;
  const int b = xcd + 8 * (t0 >> 3);
  const int g0 = strip * 8;

  // ---- stage: 3 tiles, sum 16 chunk slabs (packed u16 -> f32) ----
  const uint4* Hb = (const uint4*)Hq + (size_t)b * NCHUNK * SLAB4;
  for (int p = tid; p < SLAB4; p += 256) {          // 6 iters
    int tno = p >> 9, rem = p & 511;
    int row = rem >> 3, c8 = rem & 7;
    int R = c_itA[tno] * 64 + row;
    int C = c_jqA[tno] * 64 + c8 * 8;
    unsigned int a0=0,a1=0,a2=0,a3=0,a4=0,a5=0,a6=0,a7=0;
#pragma unroll
    for (int ch = 0; ch < NCHUNK; ch++) {
      uint4 v = Hb[(size_t)ch * SLAB4 + p];
      a0 += v.x & 0xFFFFu; a1 += v.x >> 16;
      a2 += v.y & 0xFFFFu; a3 += v.y >> 16;
      a4 += v.z & 0xFFFFu; a5 += v.z >> 16;
      a6 += v.w & 0xFFFFu; a7 += v.w >> 16;
    }
    *(float4*)&sHf[R][C]     = make_float4((float)a0,(float)a1,(float)a2,(float)a3);
    *(float4*)&sHf[R][C + 4] = make_float4((float)a4,(float)a5,(float)a6,(float)a7);
  }
  // zero quadrant (rows 64..127, cols 64..127)
  for (int q = tid; q < 1024; q += 256) {
    int row = 64 + (q >> 4), c4 = 64 + (q & 15) * 4;
    *(float4*)&sHf[row][c4] = make_float4(0.f, 0.f, 0.f, 0.f);
  }
  // S table (fixed order)
  if (tid < 128) {
    float s = 0.0f;
    for (int g = 0; g < 64; g++) s += kval(tid, g);
    sS[tid] = s;
  }
  // K strip transposed [gc][j]
  for (int idx = tid; idx < 1024; idx += 256) {
    int gc = idx >> 7, j = idx & 127;
    sKgT[gc][j] = kval(j, g0 + gc);
  }
  __syncthreads();

  // ---- M-phase partials: thread = (jh, ig, gcp); rows ig+{0,32,64,96} ----
  {
    const int jh = tid >> 7;
    const int ig = (tid >> 2) & 31;
    const int gcp = tid & 3;
    const int j0 = jh * 64;
    const int gA = gcp * 2;
    float acc[4][2];
#pragma unroll
    for (int dr = 0; dr < 4; dr++) { acc[dr][0] = 0.f; acc[dr][1] = 0.f; }
#pragma unroll 4
    for (int jt = 0; jt < 16; jt++) {
      float4 ka = *(const float4*)&sKgT[gA][j0 + jt * 4];
      float4 kb = *(const float4*)&sKgT[gA + 1][j0 + jt * 4];
#pragma unroll
      for (int dr = 0; dr < 4; dr++) {
        int i = ig + dr * 32;
        float4 h = *(const float4*)&sHf[i][j0 + jt * 4];
        acc[dr][0] = fmaf(h.x, ka.x, acc[dr][0]);
        acc[dr][0] = fmaf(h.y, ka.y, acc[dr][0]);
        acc[dr][0] = fmaf(h.z, ka.z, acc[dr][0]);
        acc[dr][0] = fmaf(h.w, ka.w, acc[dr][0]);
        acc[dr][1] = fmaf(h.x, kb.x, acc[dr][1]);
        acc[dr][1] = fmaf(h.y, kb.y, acc[dr][1]);
        acc[dr][1] = fmaf(h.z, kb.z, acc[dr][1]);
        acc[dr][1] = fmaf(h.w, kb.w, acc[dr][1]);
      }
    }
#pragma unroll
    for (int dr = 0; dr < 4; dr++) {
      int i = ig + dr * 32;
      sMp[((size_t)jh * 128 + i) * 8 + gA]     = acc[dr][0];
      sMp[((size_t)jh * 128 + i) * 8 + gA + 1] = acc[dr][1];
    }
  }
  // ---- T row-dot partial: thread = (row r2, half h) ----
  {
    int r2 = tid >> 1, h = tid & 1;
    float v = 0.0f;
#pragma unroll 4
    for (int jt = 0; jt < 16; jt++) {
      int jb = h * 64 + jt * 4;
      float4 hv = *(const float4*)&sHf[r2][jb];
      v += hv.x * sS[jb] + hv.y * sS[jb + 1] + hv.z * sS[jb + 2] + hv.w * sS[jb + 3];
    }
    sred[tid] = v * sS[r2];
  }
  __syncthreads();
  for (int st = 128; st > 0; st >>= 1) {
    if (tid < st) sred[tid] += sred[tid + st];
    __syncthreads();
  }
  // sred[0] = T (identical in every block of batch b)

  // ---- M reduce (sMp -> sM) + K_C fill (overwrites sHf; all sHf reads done) ----
  for (int e = tid; e < 1024; e += 256)
    ((float*)sM)[e] = sMp[e] + sMp[1024 + e];
  for (int idx = tid; idx < 8192; idx += 256) {
    int i = idx >> 6, r = idx & 63;
    sKC[i][r] = kval(i, r);
  }
  __syncthreads();

  // ---- epilogue partials: thread = (ih, rq, gcp); i in ih*32..+31 ----
  float* sOp = sMp;   // alias (sMp dead)
  {
    int ih = tid >> 6, rq = (tid >> 2) & 15, gcp = tid & 3;
    float o[4][2];
#pragma unroll
    for (int dr = 0; dr < 4; dr++) { o[dr][0] = 0.f; o[dr][1] = 0.f; }
#pragma unroll 8
    for (int ii = 0; ii < 32; ii++) {
      int i = ih * 32 + ii;
      float4 kc = *(const float4*)&sKC[i][rq * 4];
      float2 mv = *(const float2*)&sM[i][gcp * 2];
      o[0][0] = fmaf(kc.x, mv.x, o[0][0]); o[0][1] = fmaf(kc.x, mv.y, o[0][1]);
      o[1][0] = fmaf(kc.y, mv.x, o[1][0]); o[1][1] = fmaf(kc.y, mv.y, o[1][1]);
      o[2][0] = fmaf(kc.z, mv.x, o[2][0]); o[2][1] = fmaf(kc.z, mv.y, o[2][1]);
      o[3][0] = fmaf(kc.w, mv.x, o[3][0]); o[3][1] = fmaf(kc.w, mv.y, o[3][1]);
    }
#pragma unroll
    for (int dr = 0; dr < 4; dr++) {
      int r = rq * 4 + dr;
      sOp[((size_t)ih * 64 + r) * 8 + gcp * 2]     = o[dr][0];
      sOp[((size_t)ih * 64 + r) * 8 + gcp * 2 + 1] = o[dr][1];
    }
  }
  __syncthreads();

  // ---- combine 4 i-partials (fixed order), normalize, store ----
  {
    float inv = 1.0f / (sred[0] + EPS);
    for (int e = tid; e < 512; e += 256) {
      int r = e >> 3, gc = e & 7;
      float v = sOp[(size_t)r * 8 + gc]
              + sOp[(size_t)(64 + r) * 8 + gc]
              + sOp[(size_t)(128 + r) * 8 + gc]
              + sOp[(size_t)(192 + r) * 8 + gc];
      out[(size_t)b * 4096 + r * 64 + g0 + gc] = v * inv;
    }
  }
}

extern "C" void kernel_launch(void* const* d_in, const int* in_sizes, int n_in,
                              void* d_out, int out_size, void* d_ws, size_t ws_size,
                              hipStream_t stream) {
  const float* x = (const float*)d_in[0];
  float* out = (float*)d_out;

  unsigned int* Hq = (unsigned int*)d_ws;   // 6.3 MB

  hipFuncSetAttribute((const void*)bc_final,
                      hipFuncAttributeMaxDynamicSharedMemorySize, 85632);
  hist_full<<<256, 1024, 0, stream>>>(x, Hq);
  bc_final<<<128, 256, 85632, stream>>>(Hq, out);
}

// Round 16
// 29.635 us; speedup vs baseline: 1.0910x; 1.0910x over previous
//
#include <hip/hip_runtime.h>
#include <stdint.h>

#define BATCH 16
#define NPIX 200704      // 448*448
#define EPS 1e-6f
#define FW 128           // fine grid; i+j <= 127 structurally (chroma simplex)
#define NCHUNK 16        // pixel chunks per batch in K1
#define CHPX (NPIX / NCHUNK)     // 12544 pixels (u16-safe: < 65536)
#define CHF4 (CHPX / 4)          // 3136 float4 per plane
#define NTILE 3          // nonzero 64x64 tiles: it+jq <= 1
#define SLAB4 (NTILE * 512)      // uint4 per (b,chunk) slab

// tile list
__constant__ int c_itA[NTILE] = {0, 0, 1};
__constant__ int c_jqA[NTILE] = {0, 1, 0};

// K(c,g) = 1 / (1 + ((cc - b_g)/sigma)^2), cc=(c+0.5)/FW, b_g=g/63, 1/sigma=50
__device__ __forceinline__ float kval(int c, int g) {
  float d = (((float)c + 0.5f) * (1.0f / (float)FW) - (float)g * (1.0f / 63.0f)) * 50.0f;
  return 1.0f / (1.0f + d * d);
}

// ---------------- K1: full-grid u16 histogram per (batch, pixel-chunk) — R13 verbatim ----------------
__global__ __launch_bounds__(1024) void hist_full(const float* __restrict__ x,
                                                  unsigned int* __restrict__ Hq) {
  __shared__ unsigned int sh[8192];         // 16384 u16 bins (128x128), packed
  const int bid = blockIdx.x;
  const int tid = threadIdx.x;
  const int xcd = bid & 7;                  // batch pinned to XCD b%8
  const int t0 = bid >> 3;                  // 0..31
  const int chunk = t0 & (NCHUNK - 1);
  const int b = xcd + 8 * (t0 >> 4);

  {
    uint4* s4 = (uint4*)sh;
    uint4 z = make_uint4(0u, 0u, 0u, 0u);
    for (int t = tid; t < 2048; t += 1024) s4[t] = z;
  }
  __syncthreads();

  const float* xb = x + (size_t)b * 3 * NPIX;
  const float4* R  = (const float4*)xb + (size_t)chunk * CHF4;
  const float4* G  = (const float4*)(xb + NPIX) + (size_t)chunk * CHF4;
  const float4* Bl = (const float4*)(xb + 2 * NPIX) + (size_t)chunk * CHF4;

  for (int t = tid; t < CHF4; t += 1024) {
    float4 rv = R[t], gv = G[t], bv = Bl[t];
    float rr[4] = {rv.x, rv.y, rv.z, rv.w};
    float gg[4] = {gv.x, gv.y, gv.z, gv.w};
    float bb[4] = {bv.x, bv.y, bv.z, bv.w};
#pragma unroll
    for (int c = 0; c < 4; c++) {
      float r  = fminf(fmaxf(rr[c], 0.0f), 1.0f);
      float g  = fminf(fmaxf(gg[c], 0.0f), 1.0f);
      float bl = fminf(fmaxf(bb[c], 0.0f), 1.0f);
      float inv = 1.0f / (r + g + bl + EPS);
      int i = min((int)(r * inv * (float)FW), FW - 1);
      int j = min((int)(g * inv * (float)FW), FW - 1);
      unsigned int id = (unsigned int)((i << 7) | j);
      atomicAdd(&sh[id >> 1], 1u << ((id & 1u) << 4));   // packed u16; <=12544 adds
    }
  }
  __syncthreads();

  // flush the 3 nonzero 64x64 tiles
  const uint4* sh4 = (const uint4*)sh;
  uint4* dst = (uint4*)Hq + (size_t)(b * NCHUNK + chunk) * SLAB4;
  for (int t = tid; t < SLAB4; t += 1024) {
    int tno = t >> 9;
    int rem = t & 511;
    int row = rem >> 3, c4 = rem & 7;
    int it = c_itA[tno], jq = c_jqA[tno];
    dst[t] = sh4[(it * 64 + row) * 16 + jq * 8 + c4];
  }
}

// ---------------- K2: stage Hsum -> M-strip -> self-T -> K^T epilogue -> normalize -> out ----------------
// 256 blocks x 1024 thr: (b, strip of 4 g-cols). T computed in-block (exact by linearity,
// identical across a batch's blocks: same data, same fixed order). 80.5 KB dynamic LDS.
__global__ __launch_bounds__(1024) void bc_final(const unsigned int* __restrict__ Hq,
                                                 float* __restrict__ out) {
  extern __shared__ char smem[];
  float (*sHf)[132] = (float (*)[132])smem;              // 128x132 Hsum (f32)
  float (*sKC)[64]  = (float (*)[64])smem;               // alias: K_C [128][64] after M/T reads done
  float (*sKg)[136] = (float (*)[136])(smem + 67584);    // 4x136: K(j, g0+gc) by [gc][j]
  float* sS  = (float*)(smem + 69760);                   // 128: S(c)=sum_g K(c,g)
  float* sMp = (float*)(smem + 70272);                   // 2x128x4 M partials; alias sOp 4x64x4
  float* sM  = (float*)(smem + 74368);                   // 128x4 M strip
  float* sred = (float*)(smem + 76416);                  // 1024 (T reduction)

  const int bid = blockIdx.x;     // 256 = xcd(8) x strip(16) x bh(2)
  const int tid = threadIdx.x;
  const int xcd = bid & 7;
  const int t0 = bid >> 3;        // 0..31
  const int strip = t0 & 15;
  const int b = xcd + 8 * (t0 >> 4);
  const int g0 = strip * 4;

  // ---- stage: 3 tiles, sum 16 chunk slabs (packed u16 -> f32), 1536 uint4 positions ----
  const uint4* Hb = (const uint4*)Hq + (size_t)b * NCHUNK * SLAB4;
  for (int p = tid; p < SLAB4; p += 1024) {
    int tno = p >> 9, rem = p & 511;
    int row = rem >> 3, c8 = rem & 7;
    int R = c_itA[tno] * 64 + row;
    int C = c_jqA[tno] * 64 + c8 * 8;
    unsigned int a0=0,a1=0,a2=0,a3=0,a4=0,a5=0,a6=0,a7=0;
#pragma unroll
    for (int ch = 0; ch < NCHUNK; ch++) {
      uint4 v = Hb[(size_t)ch * SLAB4 + p];
      a0 += v.x & 0xFFFFu; a1 += v.x >> 16;
      a2 += v.y & 0xFFFFu; a3 += v.y >> 16;
      a4 += v.z & 0xFFFFu; a5 += v.z >> 16;
      a6 += v.w & 0xFFFFu; a7 += v.w >> 16;
    }
    *(float4*)&sHf[R][C]     = make_float4((float)a0,(float)a1,(float)a2,(float)a3);
    *(float4*)&sHf[R][C + 4] = make_float4((float)a4,(float)a5,(float)a6,(float)a7);
  }
  // zero quadrant (rows 64..127, cols 64..127): 1024 float4
  {
    int row = 64 + (tid >> 4), c4 = 64 + (tid & 15) * 4;
    *(float4*)&sHf[row][c4] = make_float4(0.f, 0.f, 0.f, 0.f);
  }
  // S table (fixed order)
  if (tid < 128) {
    float s = 0.0f;
    for (int g = 0; g < 64; g++) s += kval(tid, g);
    sS[tid] = s;
  }
  // K strip [gc][j]
  if (tid < 512) {
    int gc = tid >> 7, j = tid & 127;
    sKg[gc][j] = kval(j, g0 + gc);
  }
  __syncthreads();

  // ---- M partials: thread = (jh, i, gc); 64 FMA each ----
  {
    int jh = tid >> 9;            // 0..1
    int rem = tid & 511;
    int i = rem >> 2, gc = rem & 3;
    int j0 = jh * 64;
    float m = 0.0f;
#pragma unroll 4
    for (int jt = 0; jt < 16; jt++) {
      float4 h = *(const float4*)&sHf[i][j0 + jt * 4];
      float4 k = *(const float4*)&sKg[gc][j0 + jt * 4];
      m = fmaf(h.x, k.x, m); m = fmaf(h.y, k.y, m);
      m = fmaf(h.z, k.z, m); m = fmaf(h.w, k.w, m);
    }
    sMp[(size_t)jh * 512 + rem] = m;
  }
  // ---- T partials: thread = (r, j-octant) ----
  {
    int r = tid >> 3, jo = tid & 7;
    float v = 0.0f;
#pragma unroll
    for (int jt = 0; jt < 4; jt++) {
      int jb = jo * 16 + jt * 4;
      float4 hv = *(const float4*)&sHf[r][jb];
      v += hv.x * sS[jb] + hv.y * sS[jb + 1] + hv.z * sS[jb + 2] + hv.w * sS[jb + 3];
    }
    sred[tid] = v * sS[r];
  }
  __syncthreads();

  // M reduce (sMp halves -> sM); then T tree
  if (tid < 512) sM[tid] = sMp[tid] + sMp[512 + tid];
  for (int st = 512; st > 0; st >>= 1) {
    if (tid < st) sred[tid] += sred[tid + st];
    __syncthreads();
  }
  // sred[0] = T (identical for all blocks of batch b)

  // ---- K_C fill (overwrites sHf; all sHf reads complete) ----
  {
#pragma unroll
    for (int rep = 0; rep < 8; rep++) {
      int idx = rep * 1024 + tid;        // 8192 = 128 i x 64 r
      int i = idx >> 6, r = idx & 63;
      sKC[i][r] = kval(i, r);
    }
  }
  __syncthreads();

  // ---- epilogue partials: thread = (iq, r, gc); 32 FMA ----
  float* sOp = sMp;    // alias (sMp dead after sM combine)
  {
    int iq = tid >> 8;                  // 0..3
    int rem = tid & 255;
    int r = rem >> 2, gc = rem & 3;
    int i0 = iq * 32;
    float o = 0.0f;
#pragma unroll 8
    for (int ii = 0; ii < 32; ii++) {
      int i = i0 + ii;
      o = fmaf(sKC[i][r], sM[(size_t)i * 4 + gc], o);
    }
    sOp[(size_t)iq * 256 + rem] = o;
  }
  __syncthreads();

  // ---- combine 4 i-partials (fixed order), normalize, store ----
  if (tid < 256) {
    float inv = 1.0f / (sred[0] + EPS);
    float v = sOp[tid] + sOp[256 + tid] + sOp[512 + tid] + sOp[768 + tid];
    int r = tid >> 2, gc = tid & 3;
    out[(size_t)b * 4096 + r * 64 + g0 + gc] = v * inv;
  }
}

extern "C" void kernel_launch(void* const* d_in, const int* in_sizes, int n_in,
                              void* d_out, int out_size, void* d_ws, size_t ws_size,
                              hipStream_t stream) {
  const float* x = (const float*)d_in[0];
  float* out = (float*)d_out;

  unsigned int* Hq = (unsigned int*)d_ws;   // 6.3 MB

  hipFuncSetAttribute((const void*)bc_final,
                      hipFuncAttributeMaxDynamicSharedMemorySize, 80512);
  hist_full<<<256, 1024, 0, stream>>>(x, Hq);
  bc_final<<<256, 1024, 80512, stream>>>(Hq, out);
}

// Round 17
// 21.855 us; speedup vs baseline: 1.4794x; 1.3560x over previous
//
#include <hip/hip_runtime.h>
#include <stdint.h>

#define BATCH 16
#define NPIX 200704      // 448*448
#define EPS 1e-6f
#define FW 128           // fine grid; i+j <= 127 structurally (chroma simplex)
#define NCHUNK 16        // pixel chunks per batch in K1
#define CHPX (NPIX / NCHUNK)     // 12544 pixels  (u16-safe: < 65536)
#define CHF4 (CHPX / 4)          // 3136 float4 per plane
#define NTILE 3          // nonzero 64x64 tiles: it+jq <= 1
#define NSLICE 12        // 3 tiles x 4 i-quarters
#define SLAB4 (NTILE * 512)      // uint4 per (b,chunk) slab: 3 tiles x 64 rows x 8 uint4

// tile list (same order used by flush, stageBC)
__constant__ int c_itA[NTILE] = {0, 0, 1};
__constant__ int c_jqA[NTILE] = {0, 1, 0};

// K(c,g) = 1 / (1 + ((cc - b_g)/sigma)^2), cc=(c+0.5)/FW, b_g=g/63, 1/sigma=50
__device__ __forceinline__ float kval(int c, int g) {
  float d = (((float)c + 0.5f) * (1.0f / (float)FW) - (float)g * (1.0f / 63.0f)) * 50.0f;
  return 1.0f / (1.0f + d * d);
}

// ---------------- K1: full-grid u16 histogram per (batch, pixel-chunk), x read once ----------------
// LDS = 128*128 u16 bins = 32 KB static.
__global__ __launch_bounds__(1024) void hist_full(const float* __restrict__ x,
                                                  unsigned int* __restrict__ Hq) {
  __shared__ unsigned int sh[8192];         // 8192 words = 16384 u16 bins
  const int bid = blockIdx.x;
  const int tid = threadIdx.x;
  const int xcd = bid & 7;                  // batch pinned to XCD b%8
  const int t0 = bid >> 3;                  // 0..31
  const int chunk = t0 & (NCHUNK - 1);
  const int b = xcd + 8 * (t0 >> 4);

  {
    uint4* s4 = (uint4*)sh;
    uint4 z = make_uint4(0u, 0u, 0u, 0u);
    for (int t = tid; t < 2048; t += 1024) s4[t] = z;
  }
  __syncthreads();

  const float* xb = x + (size_t)b * 3 * NPIX;
  const float4* R  = (const float4*)xb + (size_t)chunk * CHF4;
  const float4* G  = (const float4*)(xb + NPIX) + (size_t)chunk * CHF4;
  const float4* Bl = (const float4*)(xb + 2 * NPIX) + (size_t)chunk * CHF4;

  for (int t = tid; t < CHF4; t += 1024) {
    float4 rv = R[t], gv = G[t], bv = Bl[t];
    float rr[4] = {rv.x, rv.y, rv.z, rv.w};
    float gg[4] = {gv.x, gv.y, gv.z, gv.w};
    float bb[4] = {bv.x, bv.y, bv.z, bv.w};
#pragma unroll
    for (int c = 0; c < 4; c++) {
      float r  = fminf(fmaxf(rr[c], 0.0f), 1.0f);
      float g  = fminf(fmaxf(gg[c], 0.0f), 1.0f);
      float bl = fminf(fmaxf(bb[c], 0.0f), 1.0f);
      float inv = 1.0f / (r + g + bl + EPS);
      int i = min((int)(r * inv * (float)FW), FW - 1);
      int j = min((int)(g * inv * (float)FW), FW - 1);
      unsigned int id = (unsigned int)((i << 7) | j);
      // packed u16: word = id>>1, half = id&1. Per-block adds = 12544 < 65536: no overflow.
      atomicAdd(&sh[id >> 1], 1u << ((id & 1u) << 4));
    }
  }
  __syncthreads();

  // flush the 3 nonzero 64x64 tiles (i+j<=127 => tiles with it+jq<=1 cover all nonzeros)
  const uint4* sh4 = (const uint4*)sh;
  uint4* dst = (uint4*)Hq + (size_t)(b * NCHUNK + chunk) * SLAB4;
  for (int t = tid; t < SLAB4; t += 1024) {        // 1536 -> 2 iters (2nd partial)
    int tno = t >> 9;                              // tile 0..2
    int rem = t & 511;
    int row = rem >> 3, c4 = rem & 7;
    int it = c_itA[tno], jq = c_jqA[tno];
    // u16 row = 128 bins = 16 uint4; col block jq*64 u16 = 8 uint4
    dst[t] = sh4[(it * 64 + row) * 16 + jq * 8 + c4];
  }
}

// ---------------- K2: fused M-GEMM + K^T epilogue, split over i-quarters ----------------
// block (b, tile sl, quarter qh): rows i in [it*64+qh*16, +16)
//   M[ip][g] = sum_{j in jq-chunk} H[i0+ip][j]*K(j,g)     (16x64, registers->LDS)
//   P[b][sl*4+qh][r][g] = sum_{ip<16} K(i0+ip, r)*M[ip][g];  psumC = slice total.
__global__ __launch_bounds__(256) void stageBC(const unsigned int* __restrict__ Hq,
                                               float* __restrict__ Pp,
                                               float* __restrict__ psumC) {
  __shared__ float sH[16][68];   // H quarter-tile (padded); M tile in epilogue
  __shared__ float sK[64][64];   // K tile; K_C (rows 0..15) in epilogue
  __shared__ float sred[256];
  const int bid = blockIdx.x;    // 192 = xcd(8) x 24;  24 = qh(4) x sl(3) x bh(2)
  const int tid = threadIdx.x;
  const int xcd = bid & 7;
  const int t0 = bid >> 3;       // 0..23
  const int qh = t0 & 3;
  const int rest = t0 >> 2;      // 0..5
  const int sl = (rest < NTILE) ? rest : rest - NTILE;
  const int b = xcd + 8 * (rest < NTILE ? 0 : 1);
  const int it = c_itA[sl];
  const int jq = c_jqA[sl];
  const int gq4 = (tid & 15) * 4;
  const int row_i = tid >> 4;            // one i-row per thread in M-phase (0..15)

  // ---- stage H quarter-tile: sum 16 chunk-partials (packed u16, tile-contiguous) ----
  if (tid < 128) {
    const uint4* Hb = (const uint4*)Hq + (size_t)b * NCHUNK * SLAB4;
    int row = tid >> 3, c8 = tid & 7;            // 128 lanes = 16 rows x 8 uint4
    int base4 = sl * 512 + (qh * 16 + row) * 8 + c8;
    unsigned int acc0[8] = {0,0,0,0,0,0,0,0};
#pragma unroll
    for (int ch = 0; ch < NCHUNK; ch++) {
      uint4 v = Hb[(size_t)ch * SLAB4 + base4];
      acc0[0] += v.x & 0xFFFFu; acc0[1] += v.x >> 16;
      acc0[2] += v.y & 0xFFFFu; acc0[3] += v.y >> 16;
      acc0[4] += v.z & 0xFFFFu; acc0[5] += v.z >> 16;
      acc0[6] += v.w & 0xFFFFu; acc0[7] += v.w >> 16;
    }
    int cc = c8 * 8;
    *(float4*)&sH[row][cc]     = make_float4((float)acc0[0], (float)acc0[1], (float)acc0[2], (float)acc0[3]);
    *(float4*)&sH[row][cc + 4] = make_float4((float)acc0[4], (float)acc0[5], (float)acc0[6], (float)acc0[7]);
  }
  // ---- K tile for j-chunk (64x64) ----
  int j0 = jq * 64;
#pragma unroll
  for (int rep = 0; rep < 4; rep++) {
    int idx = rep * 256 + tid;
    int jr = idx >> 4, g4 = (idx & 15) * 4;
    sK[jr][g4 + 0] = kval(j0 + jr, g4 + 0);
    sK[jr][g4 + 1] = kval(j0 + jr, g4 + 1);
    sK[jr][g4 + 2] = kval(j0 + jr, g4 + 2);
    sK[jr][g4 + 3] = kval(j0 + jr, g4 + 3);
  }
  __syncthreads();

  // ---- M-phase: acc[4] (1 i-row x 4 g) over 64 j ----
  float acc[4] = {0.f, 0.f, 0.f, 0.f};
#pragma unroll 4
  for (int tt = 0; tt < 16; tt++) {
    float4 hv = *(const float4*)&sH[row_i][tt * 4];
    float hh[4] = {hv.x, hv.y, hv.z, hv.w};
#pragma unroll
    for (int p = 0; p < 4; p++) {
      float4 v = *(const float4*)&sK[tt * 4 + p][gq4];
      acc[0] = fmaf(hh[p], v.x, acc[0]);
      acc[1] = fmaf(hh[p], v.y, acc[1]);
      acc[2] = fmaf(hh[p], v.z, acc[2]);
      acc[3] = fmaf(hh[p], v.w, acc[3]);
    }
  }
  __syncthreads();

  // ---- epilogue prep: M -> sH rows (16x64); K_C rows 0..15 -> sK ----
  *(float4*)&sH[row_i][gq4] = make_float4(acc[0], acc[1], acc[2], acc[3]);
  int i0f = it * 64 + qh * 16;
#pragma unroll
  for (int rep = 0; rep < 4; rep++) {           // 1024 = 16 rows x 64 r
    int idx = rep * 256 + tid;
    int ip = idx >> 6, r = idx & 63;
    sK[ip][r] = kval(i0f + ip, r);
  }
  __syncthreads();

  // ---- epilogue: P_quarter = K_C^T * M (on-chip) ----
  const int r4q = (tid >> 4) * 4;
  float acc2[4][4];
#pragma unroll
  for (int a = 0; a < 4; a++)
#pragma unroll
    for (int c = 0; c < 4; c++) acc2[a][c] = 0.0f;
#pragma unroll 4
  for (int ip = 0; ip < 16; ip++) {
    float4 kc = *(const float4*)&sK[ip][r4q];   // r-quad (broadcast in 16-lane groups)
    float4 mm = *(const float4*)&sH[ip][gq4];
    float kk2[4] = {kc.x, kc.y, kc.z, kc.w};
    float mv[4]  = {mm.x, mm.y, mm.z, mm.w};
#pragma unroll
    for (int dr = 0; dr < 4; dr++)
#pragma unroll
      for (int dg = 0; dg < 4; dg++)
        acc2[dr][dg] = fmaf(kk2[dr], mv[dg], acc2[dr][dg]);
  }

  // ---- slice sum (fixed order) + P write ----
  int sl2 = sl * 4 + qh;
  float ps = 0.0f;
#pragma unroll
  for (int dr = 0; dr < 4; dr++)
#pragma unroll
    for (int dg = 0; dg < 4; dg++) ps += acc2[dr][dg];
  sred[tid] = ps;
  __syncthreads();
  for (int st = 128; st > 0; st >>= 1) {
    if (tid < st) sred[tid] += sred[tid + st];
    __syncthreads();
  }
  if (tid == 0) psumC[b * NSLICE + sl2] = sred[0];

  float* Pb = Pp + ((size_t)b * NSLICE + sl2) * 4096;
#pragma unroll
  for (int dr = 0; dr < 4; dr++) {
    float4 v = make_float4(acc2[dr][0], acc2[dr][1], acc2[dr][2], acc2[dr][3]);
    *(float4*)&Pb[(size_t)(r4q + dr) * 64 + gq4] = v;
  }
}

// ---------------- K3: finalize — reduce 12 slices, normalize, store ----------------
__global__ __launch_bounds__(256) void finalize(const float* __restrict__ Pp,
                                                const float* __restrict__ psumC,
                                                float* __restrict__ out) {
  const int bid = blockIdx.x;        // 64 = b(16) x sl4(4); b&7 == bid&7 (XCD match)
  const int b = bid & 15;
  const int sl4 = bid >> 4;
  const int tid = threadIdx.x;
  const float* pc = psumC + b * NSLICE;
  float tot = 0.0f;
#pragma unroll
  for (int c = 0; c < NSLICE; c++) tot += pc[c];  // fixed order: deterministic
  float inv = 1.0f / (tot + EPS);
  int rg4 = sl4 * 1024 + tid * 4;
  const float* Pb = Pp + (size_t)b * NSLICE * 4096;
  float4 s = make_float4(0.f, 0.f, 0.f, 0.f);
#pragma unroll
  for (int c = 0; c < NSLICE; c++) {
    float4 v = *(const float4*)&Pb[(size_t)c * 4096 + rg4];
    s.x += v.x; s.y += v.y; s.z += v.z; s.w += v.w;
  }
  s.x *= inv; s.y *= inv; s.z *= inv; s.w *= inv;
  *(float4*)&out[(size_t)b * 4096 + rg4] = s;
}

extern "C" void kernel_launch(void* const* d_in, const int* in_sizes, int n_in,
                              void* d_out, int out_size, void* d_ws, size_t ws_size,
                              hipStream_t stream) {
  const float* x = (const float*)d_in[0];
  float* out = (float*)d_out;

  char* p = (char*)d_ws;
  unsigned int* Hq = (unsigned int*)p;  p += (size_t)BATCH * NCHUNK * SLAB4 * 16;  // 6.3 MB
  float* Pp = (float*)p;                p += (size_t)BATCH * NSLICE * 4096 * 4;    // 3.1 MB
  float* psumC = (float*)p;

  hist_full<<<256, 1024, 0, stream>>>(x, Hq);
  stageBC<<<192, 256, 0, stream>>>(Hq, Pp, psumC);
  finalize<<<64, 256, 0, stream>>>(Pp, psumC, out);
}